// Round 3
// baseline (2592.872 us; speedup 1.0000x reference)
//
#include <hip/hip_runtime.h>
#include <stdint.h>

#define DHID 64      // hidden dim, fixed by problem
#define G_BLOCKS 256 // blocks in phase-A (must equal blockDim of scan_gb_k)
#define BMAX 2048    // max buckets (bucket = 64 rows; n <= 131072)
#define RPB 64       // rows per bucket

static inline size_t align256(size_t x) { return (x + 255) & ~(size_t)255; }

// ---------------- generic helpers ----------------

__global__ void zero_f32(float* __restrict__ p, size_t n) {
  size_t i = (size_t)blockIdx.x * blockDim.x + threadIdx.x;
  if (i < n) p[i] = 0.f;
}

// ---------------- phase A: bucket partition (bucket = row >> 6) ----------------

// per-(block,bucket) histogram; LDS atomics only
__global__ void a1_hist_k(const int* __restrict__ row, int* __restrict__ histGB,
                          int nnz, int B, int chunk) {
  __shared__ int h[BMAX];
  for (int i = threadIdx.x; i < B; i += blockDim.x) h[i] = 0;
  __syncthreads();
  int g = blockIdx.x;
  int s = g * chunk, e = min(nnz, s + chunk);
  for (int j = s + threadIdx.x; j < e; j += blockDim.x)
    atomicAdd(&h[row[j] >> 6], 1);
  __syncthreads();
  for (int i = threadIdx.x; i < B; i += blockDim.x)
    histGB[i * G_BLOCKS + g] = h[i];
}

// exclusive scan across blocks within each bucket; one block per bucket
__global__ void scan_gb_k(const int* __restrict__ histGB, int* __restrict__ offGB,
                          int* __restrict__ btot, int B) {
  __shared__ int wsum[4];
  int b = blockIdx.x, t = threadIdx.x, lane = t & 63, w = t >> 6;
  int v = histGB[b * G_BLOCKS + t];
  int incl = v;
#pragma unroll
  for (int off = 1; off < 64; off <<= 1) {
    int u = __shfl_up(incl, off);
    if (lane >= off) incl += u;
  }
  if (lane == 63) wsum[w] = incl;
  __syncthreads();
  int woff = 0;
  for (int w2 = 0; w2 < w; ++w2) woff += wsum[w2];
  offGB[b * G_BLOCKS + t] = woff + incl - v;
  if (t == 0) btot[b] = wsum[0] + wsum[1] + wsum[2] + wsum[3];
}

// exclusive scan of bucket totals -> base[0..B], base[B] = nnz.
// one block, 256 threads, 8 elements/thread (covers B <= 2048).
__global__ void scan_b_k(const int* __restrict__ btot, int* __restrict__ base, int B) {
  __shared__ int wsum[4];
  int t = threadIdx.x, lane = t & 63, w = t >> 6;
  int v[8];
  int s = 0;
#pragma unroll
  for (int i = 0; i < 8; ++i) {
    int idx = t * 8 + i;
    v[i] = (idx < B) ? btot[idx] : 0;
    s += v[i];
  }
  int incl = s;
#pragma unroll
  for (int off = 1; off < 64; off <<= 1) {
    int u = __shfl_up(incl, off);
    if (lane >= off) incl += u;
  }
  if (lane == 63) wsum[w] = incl;
  __syncthreads();
  int run = incl - s;
  for (int w2 = 0; w2 < w; ++w2) run += wsum[w2];
#pragma unroll
  for (int i = 0; i < 8; ++i) {
    int idx = t * 8 + i;
    if (idx <= B) base[idx] = run;
    run += v[i];
  }
}

// scatter edges into bucket regions; each block writes only its private quota
// window per bucket (base[b] + offGB[b][g] ...), so L2 merges lines. No global atomics.
// payload packs row-low-6 into bits 24..31 of the col word (col < 2^24).
__global__ void a2_scatter_k(const int* __restrict__ row, const int* __restrict__ col,
                             const float* __restrict__ val, const int* __restrict__ base,
                             const int* __restrict__ offGB, int2* __restrict__ stage,
                             int nnz, int B, int chunk) {
  __shared__ int cur[BMAX];
  int g = blockIdx.x;
  for (int i = threadIdx.x; i < B; i += blockDim.x)
    cur[i] = base[i] + offGB[i * G_BLOCKS + g];
  __syncthreads();
  int s = g * chunk, e = min(nnz, s + chunk);
  for (int j = s + threadIdx.x; j < e; j += blockDim.x) {
    int r = row[j];
    int b = r >> 6;
    int pos = atomicAdd(&cur[b], 1);   // LDS atomic
    int2 p;
    p.x = ((r & 63) << 24) | col[j];
    p.y = __float_as_int(val[j]);
    stage[pos] = p;
  }
}

// ---------------- SpMM: one block per 64-row bucket, LDS accumulator ----------------
// Consumes bucket-staged edges directly (no within-bucket row grouping needed).
// Inner loop = round-0 proven shape: per-lane scalar float gather, 8-deep unroll.

__global__ __launch_bounds__(256) void
spmm_bucket_k(const int* __restrict__ base, const int2* __restrict__ stage,
              const float* __restrict__ x, float* __restrict__ y, int n) {
  __shared__ float acc[RPB * DHID];   // 16 KB
  int b = blockIdx.x;
  int t = threadIdx.x, lane = t & 63;
  int wid = __builtin_amdgcn_readfirstlane(t >> 6);
  // zero accumulator
  float4* accv = (float4*)acc;
  for (int i = t; i < RPB * DHID / 4; i += 256) {
    float4 z; z.x = 0.f; z.y = 0.f; z.z = 0.f; z.w = 0.f;
    accv[i] = z;
  }
  __syncthreads();
  int s = __builtin_amdgcn_readfirstlane(base[b]);
  int e = __builtin_amdgcn_readfirstlane(base[b + 1]);
  int cnt = e - s;
  int per = (cnt + 3) >> 2;
  int ks = s + wid * per;
  int ke = min(e, ks + per);
  int k = ks;
  for (; k + 8 <= ke; k += 8) {
    int2 p0 = stage[k + 0], p1 = stage[k + 1], p2 = stage[k + 2], p3 = stage[k + 3];
    int2 p4 = stage[k + 4], p5 = stage[k + 5], p6 = stage[k + 6], p7 = stage[k + 7];
    float x0 = x[((size_t)(p0.x & 0xFFFFFF) << 6) + lane];
    float x1 = x[((size_t)(p1.x & 0xFFFFFF) << 6) + lane];
    float x2 = x[((size_t)(p2.x & 0xFFFFFF) << 6) + lane];
    float x3 = x[((size_t)(p3.x & 0xFFFFFF) << 6) + lane];
    float x4 = x[((size_t)(p4.x & 0xFFFFFF) << 6) + lane];
    float x5 = x[((size_t)(p5.x & 0xFFFFFF) << 6) + lane];
    float x6 = x[((size_t)(p6.x & 0xFFFFFF) << 6) + lane];
    float x7 = x[((size_t)(p7.x & 0xFFFFFF) << 6) + lane];
    atomicAdd(&acc[((((unsigned)p0.x) >> 24) << 6) + lane], __int_as_float(p0.y) * x0);
    atomicAdd(&acc[((((unsigned)p1.x) >> 24) << 6) + lane], __int_as_float(p1.y) * x1);
    atomicAdd(&acc[((((unsigned)p2.x) >> 24) << 6) + lane], __int_as_float(p2.y) * x2);
    atomicAdd(&acc[((((unsigned)p3.x) >> 24) << 6) + lane], __int_as_float(p3.y) * x3);
    atomicAdd(&acc[((((unsigned)p4.x) >> 24) << 6) + lane], __int_as_float(p4.y) * x4);
    atomicAdd(&acc[((((unsigned)p5.x) >> 24) << 6) + lane], __int_as_float(p5.y) * x5);
    atomicAdd(&acc[((((unsigned)p6.x) >> 24) << 6) + lane], __int_as_float(p6.y) * x6);
    atomicAdd(&acc[((((unsigned)p7.x) >> 24) << 6) + lane], __int_as_float(p7.y) * x7);
  }
  for (; k < ke; ++k) {
    int2 p = stage[k];
    float xv = x[((size_t)(p.x & 0xFFFFFF) << 6) + lane];
    atomicAdd(&acc[((((unsigned)p.x) >> 24) << 6) + lane], __int_as_float(p.y) * xv);
  }
  __syncthreads();
  // writeout: 64 rows x 64 floats, coalesced float4
  for (int i = t; i < RPB * DHID / 4; i += 256) {
    int r = (b << 6) + (i >> 4);
    if (r < n)
      *(float4*)(&y[((size_t)r << 6) + ((size_t)(i & 15) << 2)]) = accv[i];
  }
}

__global__ __launch_bounds__(256) void
spmm_bucket_fused_k(const int* __restrict__ base, const int2* __restrict__ stage,
                    const float* __restrict__ e0, const float* __restrict__ e1,
                    float* __restrict__ e2, float* __restrict__ summed,
                    float* __restrict__ e0out, int n) {
  __shared__ float acc[RPB * DHID];   // 16 KB
  int b = blockIdx.x;
  int t = threadIdx.x, lane = t & 63;
  int wid = __builtin_amdgcn_readfirstlane(t >> 6);
  float4* accv = (float4*)acc;
  for (int i = t; i < RPB * DHID / 4; i += 256) {
    float4 z; z.x = 0.f; z.y = 0.f; z.z = 0.f; z.w = 0.f;
    accv[i] = z;
  }
  __syncthreads();
  int s = __builtin_amdgcn_readfirstlane(base[b]);
  int e = __builtin_amdgcn_readfirstlane(base[b + 1]);
  int cnt = e - s;
  int per = (cnt + 3) >> 2;
  int ks = s + wid * per;
  int ke = min(e, ks + per);
  int k = ks;
  for (; k + 8 <= ke; k += 8) {
    int2 p0 = stage[k + 0], p1 = stage[k + 1], p2 = stage[k + 2], p3 = stage[k + 3];
    int2 p4 = stage[k + 4], p5 = stage[k + 5], p6 = stage[k + 6], p7 = stage[k + 7];
    float x0 = e1[((size_t)(p0.x & 0xFFFFFF) << 6) + lane];
    float x1 = e1[((size_t)(p1.x & 0xFFFFFF) << 6) + lane];
    float x2 = e1[((size_t)(p2.x & 0xFFFFFF) << 6) + lane];
    float x3 = e1[((size_t)(p3.x & 0xFFFFFF) << 6) + lane];
    float x4 = e1[((size_t)(p4.x & 0xFFFFFF) << 6) + lane];
    float x5 = e1[((size_t)(p5.x & 0xFFFFFF) << 6) + lane];
    float x6 = e1[((size_t)(p6.x & 0xFFFFFF) << 6) + lane];
    float x7 = e1[((size_t)(p7.x & 0xFFFFFF) << 6) + lane];
    atomicAdd(&acc[((((unsigned)p0.x) >> 24) << 6) + lane], __int_as_float(p0.y) * x0);
    atomicAdd(&acc[((((unsigned)p1.x) >> 24) << 6) + lane], __int_as_float(p1.y) * x1);
    atomicAdd(&acc[((((unsigned)p2.x) >> 24) << 6) + lane], __int_as_float(p2.y) * x2);
    atomicAdd(&acc[((((unsigned)p3.x) >> 24) << 6) + lane], __int_as_float(p3.y) * x3);
    atomicAdd(&acc[((((unsigned)p4.x) >> 24) << 6) + lane], __int_as_float(p4.y) * x4);
    atomicAdd(&acc[((((unsigned)p5.x) >> 24) << 6) + lane], __int_as_float(p5.y) * x5);
    atomicAdd(&acc[((((unsigned)p6.x) >> 24) << 6) + lane], __int_as_float(p6.y) * x6);
    atomicAdd(&acc[((((unsigned)p7.x) >> 24) << 6) + lane], __int_as_float(p7.y) * x7);
  }
  for (; k < ke; ++k) {
    int2 p = stage[k];
    float xv = e1[((size_t)(p.x & 0xFFFFFF) << 6) + lane];
    atomicAdd(&acc[((((unsigned)p.x) >> 24) << 6) + lane], __int_as_float(p.y) * xv);
  }
  __syncthreads();
  // fused epilogue: e2 = acc; summed = e0 + e1 + acc; e0out = e0
  for (int i = t; i < RPB * DHID / 4; i += 256) {
    int r = (b << 6) + (i >> 4);
    if (r < n) {
      size_t o = ((size_t)r << 6) + ((size_t)(i & 15) << 2);
      float4 c = accv[i];
      float4 a = *(const float4*)(e0 + o);
      float4 bb = *(const float4*)(e1 + o);
      float4 sm;
      sm.x = a.x + bb.x + c.x;
      sm.y = a.y + bb.y + c.y;
      sm.z = a.z + bb.z + c.z;
      sm.w = a.w + bb.w + c.w;
      *(float4*)(e2 + o)     = c;
      *(float4*)(summed + o) = sm;
      *(float4*)(e0out + o)  = a;
    }
  }
}

// ---------------- fallback: atomic path ----------------

__global__ void spmm_atomic_k(const int* __restrict__ row, const int* __restrict__ col,
                              const float* __restrict__ val, const float* __restrict__ x,
                              float* __restrict__ y, int nnz) {
  int wave = (blockIdx.x * blockDim.x + threadIdx.x) >> 6;
  int lane = threadIdx.x & 63;
  if (wave >= nnz) return;
  int r = row[wave]; int c = col[wave]; float v = val[wave];
  atomicAdd(&y[(size_t)r * DHID + lane], v * x[(size_t)c * DHID + lane]);
}

__global__ void sum_k(const float4* __restrict__ e0, const float4* __restrict__ e1,
                      const float4* __restrict__ e2, float4* __restrict__ summed,
                      float4* __restrict__ e0out, int n4) {
  int i = blockIdx.x * blockDim.x + threadIdx.x;
  if (i < n4) {
    float4 a = e0[i], b = e1[i], c = e2[i];
    float4 s;
    s.x = a.x + b.x + c.x;
    s.y = a.y + b.y + c.y;
    s.z = a.z + b.z + c.z;
    s.w = a.w + b.w + c.w;
    summed[i] = s;
    e0out[i] = a;
  }
}

extern "C" void kernel_launch(void* const* d_in, const int* in_sizes, int n_in,
                              void* d_out, int out_size, void* d_ws, size_t ws_size,
                              hipStream_t stream) {
  const int*   row = (const int*)d_in[0];
  const int*   col = (const int*)d_in[1];
  const float* val = (const float*)d_in[2];
  const float* emb = (const float*)d_in[3];
  int nnz = in_sizes[0];
  int n   = in_sizes[3] / DHID;
  size_t ND = (size_t)n * DHID;

  float* out    = (float*)d_out;
  float* summed = out;
  float* e0o    = out + ND;
  float* e1     = out + 2 * ND;
  float* e2     = out + 3 * ND;

  int B  = (n + RPB - 1) / RPB;     // buckets of 64 rows
  int chunk = (nnz + G_BLOCKS - 1) / G_BLOCKS;

  // carve workspace
  size_t o0 = 0;
  size_t histGB_off = o0; o0 += align256((size_t)BMAX * G_BLOCKS * 4);
  size_t offGB_off  = o0; o0 += align256((size_t)BMAX * G_BLOCKS * 4);
  size_t btot_off   = o0; o0 += align256((size_t)BMAX * 4);
  size_t base_off   = o0; o0 += align256((size_t)(BMAX + 1) * 4);
  size_t stage_off  = o0; o0 += align256((size_t)nnz * 8);
  size_t need_sorted = o0;

  bool use_sorted = (ws_size >= need_sorted) && (B <= BMAX) && (n < (1 << 24));

  int n4 = (int)(ND / 4);
  int sb = (n4 + 255) / 256;
  int wb = (int)(((size_t)nnz * 64 + 255) / 256);

  if (use_sorted) {
    uint8_t* w = (uint8_t*)d_ws;
    int*  histGB = (int*)(w + histGB_off);
    int*  offGB  = (int*)(w + offGB_off);
    int*  btot   = (int*)(w + btot_off);
    int*  base   = (int*)(w + base_off);
    int2* stage  = (int2*)(w + stage_off);

    // phase A: partition into 64-row buckets, zero global atomics
    a1_hist_k<<<G_BLOCKS, 256, 0, stream>>>(row, histGB, nnz, B, chunk);
    scan_gb_k<<<B, 256, 0, stream>>>(histGB, offGB, btot, B);
    scan_b_k<<<1, 256, 0, stream>>>(btot, base, B);
    a2_scatter_k<<<G_BLOCKS, 256, 0, stream>>>(row, col, val, base, offGB, stage,
                                               nnz, B, chunk);

    // SpMM x2 directly on bucket-staged edges (layer 2 fuses the epilogue)
    spmm_bucket_k<<<B, 256, 0, stream>>>(base, stage, emb, e1, n);
    spmm_bucket_fused_k<<<B, 256, 0, stream>>>(base, stage, emb, e1, e2, summed, e0o, n);
  } else {
    zero_f32<<<(int)((ND + 255) / 256), 256, 0, stream>>>(e1, ND);
    spmm_atomic_k<<<wb, 256, 0, stream>>>(row, col, val, emb, e1, nnz);
    zero_f32<<<(int)((ND + 255) / 256), 256, 0, stream>>>(e2, ND);
    spmm_atomic_k<<<wb, 256, 0, stream>>>(row, col, val, e1, e2, nnz);
    sum_k<<<sb, 256, 0, stream>>>((const float4*)emb, (const float4*)e1,
                                  (const float4*)e2, (float4*)summed,
                                  (float4*)e0o, n4);
  }
}

// Round 4
// 692.276 us; speedup vs baseline: 3.7454x; 3.7454x over previous
//
#include <hip/hip_runtime.h>
#include <stdint.h>

#define DHID 64      // hidden dim, fixed by problem

static inline size_t align256(size_t x) { return (x + 255) & ~(size_t)255; }

// ---------------- generic helpers ----------------

__global__ void zero_i32(int* __restrict__ p, int n) {
  int i = blockIdx.x * blockDim.x + threadIdx.x;
  if (i < n) p[i] = 0;
}

__global__ void zero_f32(float* __restrict__ p, size_t n) {
  size_t i = (size_t)blockIdx.x * blockDim.x + threadIdx.x;
  if (i < n) p[i] = 0.f;
}

// ---------------- preprocessing: direct CSR build ----------------

// per-row counts via global atomics (spread over n counters -> all L2 channels)
__global__ void hist_k(const int* __restrict__ row, int* __restrict__ count, int nnz) {
  int i = blockIdx.x * blockDim.x + threadIdx.x;
  int stride = gridDim.x * blockDim.x;
  for (int j = i; j < nnz; j += stride)
    atomicAdd(&count[row[j]], 1);
}

// row scan (count -> rowstart), n up to 64*2048
__global__ void scan1_k(const int* __restrict__ count, int* __restrict__ bsum, int n) {
  __shared__ int lds[4];
  int base = blockIdx.x * 2048 + threadIdx.x * 8;
  int s = 0;
#pragma unroll
  for (int i = 0; i < 8; ++i) { int idx = base + i; if (idx < n) s += count[idx]; }
#pragma unroll
  for (int off = 32; off > 0; off >>= 1) s += __shfl_down(s, off);
  if ((threadIdx.x & 63) == 0) lds[threadIdx.x >> 6] = s;
  __syncthreads();
  if (threadIdx.x == 0) bsum[blockIdx.x] = lds[0] + lds[1] + lds[2] + lds[3];
}

__global__ void scan2_k(int* __restrict__ bsum, int nb, int* __restrict__ rowstart, int n) {
  int lane = threadIdx.x;
  int v = (lane < nb) ? bsum[lane] : 0;
  int incl = v;
#pragma unroll
  for (int off = 1; off < 64; off <<= 1) {
    int t = __shfl_up(incl, off);
    if (lane >= off) incl += t;
  }
  if (lane < nb) bsum[lane] = incl - v;
  if (lane == 63) rowstart[n] = incl;
}

// writes rowstart AND a scratch cursor copy (consumed by scatter_k)
__global__ void scan3_k(const int* __restrict__ count, const int* __restrict__ bsum,
                        int* __restrict__ rowstart, int* __restrict__ cursor, int n) {
  __shared__ int wsum[4];
  int base = blockIdx.x * 2048 + threadIdx.x * 8;
  int vals[8];
  int s = 0;
#pragma unroll
  for (int i = 0; i < 8; ++i) { int idx = base + i; vals[i] = (idx < n) ? count[idx] : 0; s += vals[i]; }
  int lane = threadIdx.x & 63, wid = threadIdx.x >> 6;
  int incl = s;
#pragma unroll
  for (int off = 1; off < 64; off <<= 1) {
    int t = __shfl_up(incl, off);
    if (lane >= off) incl += t;
  }
  if (lane == 63) wsum[wid] = incl;
  __syncthreads();
  int run = bsum[blockIdx.x] + (incl - s);
  for (int w = 0; w < wid; ++w) run += wsum[w];
#pragma unroll
  for (int i = 0; i < 8; ++i) {
    int idx = base + i;
    if (idx < n) { rowstart[idx] = run; cursor[idx] = run; }
    run += vals[i];
  }
}

// single-pass scatter into row-grouped edges via global atomic cursors.
// writes are random 8B but row-clustered; edges (~26MB) ~fits aggregate L2 so
// partial lines merge before writeback.
__global__ void scatter_k(const int* __restrict__ row, const int* __restrict__ col,
                          const float* __restrict__ val, int* __restrict__ cursor,
                          int2* __restrict__ edges, int nnz) {
  int i = blockIdx.x * blockDim.x + threadIdx.x;
  int stride = gridDim.x * blockDim.x;
  for (int j = i; j < nnz; j += stride) {
    int r = row[j];
    int pos = atomicAdd(&cursor[r], 1);
    int2 q;
    q.x = col[j];
    q.y = __float_as_int(val[j]);
    edges[pos] = q;
  }
}

// ---------------- SpMM: one wave per row (round-0 proven shape) ----------------

__global__ void spmm_k(const int* __restrict__ rowstart, const int2* __restrict__ edges,
                       const float* __restrict__ x, float* __restrict__ y, int n) {
  int wave = (blockIdx.x * blockDim.x + threadIdx.x) >> 6;
  int lane = threadIdx.x & 63;
  if (wave >= n) return;
  int start = __builtin_amdgcn_readfirstlane(rowstart[wave]);
  int end   = __builtin_amdgcn_readfirstlane(rowstart[wave + 1]);
  float acc = 0.f;
  int k = start;
  for (; k + 8 <= end; k += 8) {
    int2 e0 = edges[k + 0], e1 = edges[k + 1], e2 = edges[k + 2], e3 = edges[k + 3];
    int2 e4 = edges[k + 4], e5 = edges[k + 5], e6 = edges[k + 6], e7 = edges[k + 7];
    float x0 = x[((size_t)e0.x << 6) + lane];
    float x1 = x[((size_t)e1.x << 6) + lane];
    float x2 = x[((size_t)e2.x << 6) + lane];
    float x3 = x[((size_t)e3.x << 6) + lane];
    float x4 = x[((size_t)e4.x << 6) + lane];
    float x5 = x[((size_t)e5.x << 6) + lane];
    float x6 = x[((size_t)e6.x << 6) + lane];
    float x7 = x[((size_t)e7.x << 6) + lane];
    acc += __int_as_float(e0.y) * x0;
    acc += __int_as_float(e1.y) * x1;
    acc += __int_as_float(e2.y) * x2;
    acc += __int_as_float(e3.y) * x3;
    acc += __int_as_float(e4.y) * x4;
    acc += __int_as_float(e5.y) * x5;
    acc += __int_as_float(e6.y) * x6;
    acc += __int_as_float(e7.y) * x7;
  }
  for (; k < end; ++k) {
    int2 e = edges[k];
    acc += __int_as_float(e.y) * x[((size_t)e.x << 6) + lane];
  }
  y[((size_t)wave << 6) + lane] = acc;
}

__global__ void spmm_fused_k(const int* __restrict__ rowstart, const int2* __restrict__ edges,
                             const float* __restrict__ e0, const float* __restrict__ e1,
                             float* __restrict__ e2, float* __restrict__ summed,
                             float* __restrict__ e0out, int n) {
  int wave = (blockIdx.x * blockDim.x + threadIdx.x) >> 6;
  int lane = threadIdx.x & 63;
  if (wave >= n) return;
  int start = __builtin_amdgcn_readfirstlane(rowstart[wave]);
  int end   = __builtin_amdgcn_readfirstlane(rowstart[wave + 1]);
  float acc = 0.f;
  int k = start;
  for (; k + 8 <= end; k += 8) {
    int2 ea = edges[k + 0], eb = edges[k + 1], ec = edges[k + 2], ed = edges[k + 3];
    int2 ee = edges[k + 4], ef = edges[k + 5], eg = edges[k + 6], eh = edges[k + 7];
    float x0 = e1[((size_t)ea.x << 6) + lane];
    float x1 = e1[((size_t)eb.x << 6) + lane];
    float x2 = e1[((size_t)ec.x << 6) + lane];
    float x3 = e1[((size_t)ed.x << 6) + lane];
    float x4 = e1[((size_t)ee.x << 6) + lane];
    float x5 = e1[((size_t)ef.x << 6) + lane];
    float x6 = e1[((size_t)eg.x << 6) + lane];
    float x7 = e1[((size_t)eh.x << 6) + lane];
    acc += __int_as_float(ea.y) * x0;
    acc += __int_as_float(eb.y) * x1;
    acc += __int_as_float(ec.y) * x2;
    acc += __int_as_float(ed.y) * x3;
    acc += __int_as_float(ee.y) * x4;
    acc += __int_as_float(ef.y) * x5;
    acc += __int_as_float(eg.y) * x6;
    acc += __int_as_float(eh.y) * x7;
  }
  for (; k < end; ++k) {
    int2 e = edges[k];
    acc += __int_as_float(e.y) * e1[((size_t)e.x << 6) + lane];
  }
  size_t o = ((size_t)wave << 6) + lane;
  float v0 = e0[o];
  float v1 = e1[o];
  e2[o] = acc;
  summed[o] = v0 + v1 + acc;
  e0out[o] = v0;
}

// ---------------- fallback: atomic path ----------------

__global__ void spmm_atomic_k(const int* __restrict__ row, const int* __restrict__ col,
                              const float* __restrict__ val, const float* __restrict__ x,
                              float* __restrict__ y, int nnz) {
  int wave = (blockIdx.x * blockDim.x + threadIdx.x) >> 6;
  int lane = threadIdx.x & 63;
  if (wave >= nnz) return;
  int r = row[wave]; int c = col[wave]; float v = val[wave];
  atomicAdd(&y[(size_t)r * DHID + lane], v * x[(size_t)c * DHID + lane]);
}

__global__ void sum_k(const float4* __restrict__ e0, const float4* __restrict__ e1,
                      const float4* __restrict__ e2, float4* __restrict__ summed,
                      float4* __restrict__ e0out, int n4) {
  int i = blockIdx.x * blockDim.x + threadIdx.x;
  if (i < n4) {
    float4 a = e0[i], b = e1[i], c = e2[i];
    float4 s;
    s.x = a.x + b.x + c.x;
    s.y = a.y + b.y + c.y;
    s.z = a.z + b.z + c.z;
    s.w = a.w + b.w + c.w;
    summed[i] = s;
    e0out[i] = a;
  }
}

extern "C" void kernel_launch(void* const* d_in, const int* in_sizes, int n_in,
                              void* d_out, int out_size, void* d_ws, size_t ws_size,
                              hipStream_t stream) {
  const int*   row = (const int*)d_in[0];
  const int*   col = (const int*)d_in[1];
  const float* val = (const float*)d_in[2];
  const float* emb = (const float*)d_in[3];
  int nnz = in_sizes[0];
  int n   = in_sizes[3] / DHID;
  size_t ND = (size_t)n * DHID;

  float* out    = (float*)d_out;
  float* summed = out;
  float* e0o    = out + ND;
  float* e1     = out + 2 * ND;
  float* e2     = out + 3 * ND;

  int nb = (n + 2047) / 2048;       // row-scan blocks

  // carve workspace
  size_t o0 = 0;
  size_t count_off    = o0; o0 += align256((size_t)(n + 1) * 4);
  size_t rowstart_off = o0; o0 += align256((size_t)(n + 1) * 4);
  size_t cursor_off   = o0; o0 += align256((size_t)(n + 1) * 4);
  size_t bsum_off     = o0; o0 += align256(256 * 4);
  size_t edges_off    = o0; o0 += align256((size_t)nnz * 8);
  size_t need_sorted = o0;

  bool use_sorted = (ws_size >= need_sorted) && (nb <= 64);

  int rb = (int)((ND + 255) / 256);   // wave-per-row: n*64 threads
  int n4 = (int)(ND / 4);
  int sb = (n4 + 255) / 256;
  int wb = (int)(((size_t)nnz * 64 + 255) / 256);

  if (use_sorted) {
    uint8_t* w = (uint8_t*)d_ws;
    int*  count    = (int*)(w + count_off);
    int*  rowstart = (int*)(w + rowstart_off);
    int*  cursor   = (int*)(w + cursor_off);
    int*  bsum     = (int*)(w + bsum_off);
    int2* edges    = (int2*)(w + edges_off);

    // direct CSR build: hist -> scan -> single scatter
    zero_i32<<<(n + 255) / 256, 256, 0, stream>>>(count, n);
    hist_k<<<2048, 256, 0, stream>>>(row, count, nnz);
    scan1_k<<<nb, 256, 0, stream>>>(count, bsum, n);
    scan2_k<<<1, 64, 0, stream>>>(bsum, nb, rowstart, n);
    scan3_k<<<nb, 256, 0, stream>>>(count, bsum, rowstart, cursor, n);
    scatter_k<<<2048, 256, 0, stream>>>(row, col, val, cursor, edges, nnz);

    // SpMM x2 (layer 2 fuses the e0+e1+e2 epilogue)
    spmm_k<<<rb, 256, 0, stream>>>(rowstart, edges, emb, e1, n);
    spmm_fused_k<<<rb, 256, 0, stream>>>(rowstart, edges, emb, e1, e2, summed, e0o, n);
  } else {
    zero_f32<<<(int)((ND + 255) / 256), 256, 0, stream>>>(e1, ND);
    spmm_atomic_k<<<wb, 256, 0, stream>>>(row, col, val, emb, e1, nnz);
    zero_f32<<<(int)((ND + 255) / 256), 256, 0, stream>>>(e2, ND);
    spmm_atomic_k<<<wb, 256, 0, stream>>>(row, col, val, e1, e2, nnz);
    sum_k<<<sb, 256, 0, stream>>>((const float4*)emb, (const float4*)e1,
                                  (const float4*)e2, (float4*)summed,
                                  (float4*)e0o, n4);
  }
}

// Round 5
// 492.217 us; speedup vs baseline: 5.2677x; 1.4064x over previous
//
#include <hip/hip_runtime.h>
#include <stdint.h>

#define DHID 64      // hidden dim, fixed by problem
#define G_BLOCKS 256 // blocks in phase-A (must equal blockDim of scan_gb_k)
#define BMAX 2048    // max buckets (bucket = 64 rows; n <= 131072)
#define RPB 64       // rows per bucket

static inline size_t align256(size_t x) { return (x + 255) & ~(size_t)255; }

// ---------------- generic helpers ----------------

__global__ void zero_f32(float* __restrict__ p, size_t n) {
  size_t i = (size_t)blockIdx.x * blockDim.x + threadIdx.x;
  if (i < n) p[i] = 0.f;
}

// ---------------- phase A: bucket partition (bucket = row >> 6) ----------------
// (all four kernels ran verified in round 3)

// per-(block,bucket) histogram; LDS atomics only
__global__ void a1_hist_k(const int* __restrict__ row, int* __restrict__ histGB,
                          int nnz, int B, int chunk) {
  __shared__ int h[BMAX];
  for (int i = threadIdx.x; i < B; i += blockDim.x) h[i] = 0;
  __syncthreads();
  int g = blockIdx.x;
  int s = g * chunk, e = min(nnz, s + chunk);
  for (int j = s + threadIdx.x; j < e; j += blockDim.x)
    atomicAdd(&h[row[j] >> 6], 1);
  __syncthreads();
  for (int i = threadIdx.x; i < B; i += blockDim.x)
    histGB[i * G_BLOCKS + g] = h[i];
}

// exclusive scan across blocks within each bucket; one block per bucket
__global__ void scan_gb_k(const int* __restrict__ histGB, int* __restrict__ offGB,
                          int* __restrict__ btot, int B) {
  __shared__ int wsum[4];
  int b = blockIdx.x, t = threadIdx.x, lane = t & 63, w = t >> 6;
  int v = histGB[b * G_BLOCKS + t];
  int incl = v;
#pragma unroll
  for (int off = 1; off < 64; off <<= 1) {
    int u = __shfl_up(incl, off);
    if (lane >= off) incl += u;
  }
  if (lane == 63) wsum[w] = incl;
  __syncthreads();
  int woff = 0;
  for (int w2 = 0; w2 < w; ++w2) woff += wsum[w2];
  offGB[b * G_BLOCKS + t] = woff + incl - v;
  if (t == 0) btot[b] = wsum[0] + wsum[1] + wsum[2] + wsum[3];
}

// exclusive scan of bucket totals -> base[0..B], base[B] = nnz.
// one block, 256 threads, 8 elements/thread (covers B <= 2048).
__global__ void scan_b_k(const int* __restrict__ btot, int* __restrict__ base, int B) {
  __shared__ int wsum[4];
  int t = threadIdx.x, lane = t & 63, w = t >> 6;
  int v[8];
  int s = 0;
#pragma unroll
  for (int i = 0; i < 8; ++i) {
    int idx = t * 8 + i;
    v[i] = (idx < B) ? btot[idx] : 0;
    s += v[i];
  }
  int incl = s;
#pragma unroll
  for (int off = 1; off < 64; off <<= 1) {
    int u = __shfl_up(incl, off);
    if (lane >= off) incl += u;
  }
  if (lane == 63) wsum[w] = incl;
  __syncthreads();
  int run = incl - s;
  for (int w2 = 0; w2 < w; ++w2) run += wsum[w2];
#pragma unroll
  for (int i = 0; i < 8; ++i) {
    int idx = t * 8 + i;
    if (idx <= B) base[idx] = run;
    run += v[i];
  }
}

// scatter edges into bucket regions; each block writes only its private quota
// window per bucket (base[b] + offGB[b][g] ...), so L2 merges lines. No global atomics.
// payload packs row-low-6 into bits 24..29 of the col word (col < 2^24).
__global__ void a2_scatter_k(const int* __restrict__ row, const int* __restrict__ col,
                             const float* __restrict__ val, const int* __restrict__ base,
                             const int* __restrict__ offGB, int2* __restrict__ stage,
                             int nnz, int B, int chunk) {
  __shared__ int cur[BMAX];
  int g = blockIdx.x;
  for (int i = threadIdx.x; i < B; i += blockDim.x)
    cur[i] = base[i] + offGB[i * G_BLOCKS + g];
  __syncthreads();
  int s = g * chunk, e = min(nnz, s + chunk);
  for (int j = s + threadIdx.x; j < e; j += blockDim.x) {
    int r = row[j];
    int b = r >> 6;
    int pos = atomicAdd(&cur[b], 1);   // LDS atomic
    int2 p;
    p.x = ((r & 63) << 24) | col[j];
    p.y = __float_as_int(val[j]);
    stage[pos] = p;
  }
}

// ---------------- phase B (fused): within-bucket row grouping, ONE kernel ----------------
// Per 64-row bucket: LDS histogram -> wave-0 scan -> emit rowstart -> re-read bucket
// (16KB, L2-hot) -> scatter into private contiguous edges window.

__global__ __launch_bounds__(256) void
bgroup_k(const int* __restrict__ base, const int2* __restrict__ stage,
         int2* __restrict__ edges, int* __restrict__ rowstart, int n, int nnz) {
  __shared__ int h[RPB];
  __shared__ int cur[RPB];
  int b = blockIdx.x, t = threadIdx.x;
  if (t < RPB) h[t] = 0;
  __syncthreads();
  int s = base[b], e = base[b + 1];
  for (int j = s + t; j < e; j += 256)
    atomicAdd(&h[((unsigned)stage[j].x) >> 24], 1);
  __syncthreads();
  if (t < RPB) {               // exactly wave 0 (t = lane)
    int v = h[t];
    int incl = v;
#pragma unroll
    for (int off = 1; off < 64; off <<= 1) {
      int u = __shfl_up(incl, off);
      if (t >= off) incl += u;
    }
    int excl = incl - v;
    cur[t] = s + excl;
    int r = (b << 6) + t;
    if (r < n) rowstart[r] = s + excl;
  }
  if (b == 0 && t == 0) rowstart[n] = nnz;
  __syncthreads();
  for (int j = s + t; j < e; j += 256) {
    int2 p = stage[j];
    int rlow = ((unsigned)p.x) >> 24;
    int pos = atomicAdd(&cur[rlow], 1);  // LDS atomic
    int2 q;
    q.x = p.x & 0xFFFFFF;
    q.y = p.y;
    edges[pos] = q;
  }
}

// ---------------- SpMM: one wave per row (round-0 proven shape, verbatim) ----------------

__global__ void spmm_k(const int* __restrict__ rowstart, const int2* __restrict__ edges,
                       const float* __restrict__ x, float* __restrict__ y, int n) {
  int wave = (blockIdx.x * blockDim.x + threadIdx.x) >> 6;
  int lane = threadIdx.x & 63;
  if (wave >= n) return;
  int start = __builtin_amdgcn_readfirstlane(rowstart[wave]);
  int end   = __builtin_amdgcn_readfirstlane(rowstart[wave + 1]);
  float acc = 0.f;
  int k = start;
  for (; k + 8 <= end; k += 8) {
    int2 e0 = edges[k + 0], e1 = edges[k + 1], e2 = edges[k + 2], e3 = edges[k + 3];
    int2 e4 = edges[k + 4], e5 = edges[k + 5], e6 = edges[k + 6], e7 = edges[k + 7];
    float x0 = x[((size_t)e0.x << 6) + lane];
    float x1 = x[((size_t)e1.x << 6) + lane];
    float x2 = x[((size_t)e2.x << 6) + lane];
    float x3 = x[((size_t)e3.x << 6) + lane];
    float x4 = x[((size_t)e4.x << 6) + lane];
    float x5 = x[((size_t)e5.x << 6) + lane];
    float x6 = x[((size_t)e6.x << 6) + lane];
    float x7 = x[((size_t)e7.x << 6) + lane];
    acc += __int_as_float(e0.y) * x0;
    acc += __int_as_float(e1.y) * x1;
    acc += __int_as_float(e2.y) * x2;
    acc += __int_as_float(e3.y) * x3;
    acc += __int_as_float(e4.y) * x4;
    acc += __int_as_float(e5.y) * x5;
    acc += __int_as_float(e6.y) * x6;
    acc += __int_as_float(e7.y) * x7;
  }
  for (; k < end; ++k) {
    int2 e = edges[k];
    acc += __int_as_float(e.y) * x[((size_t)e.x << 6) + lane];
  }
  y[((size_t)wave << 6) + lane] = acc;
}

__global__ void spmm_fused_k(const int* __restrict__ rowstart, const int2* __restrict__ edges,
                             const float* __restrict__ e0, const float* __restrict__ e1,
                             float* __restrict__ e2, float* __restrict__ summed,
                             float* __restrict__ e0out, int n) {
  int wave = (blockIdx.x * blockDim.x + threadIdx.x) >> 6;
  int lane = threadIdx.x & 63;
  if (wave >= n) return;
  int start = __builtin_amdgcn_readfirstlane(rowstart[wave]);
  int end   = __builtin_amdgcn_readfirstlane(rowstart[wave + 1]);
  float acc = 0.f;
  int k = start;
  for (; k + 8 <= end; k += 8) {
    int2 ea = edges[k + 0], eb = edges[k + 1], ec = edges[k + 2], ed = edges[k + 3];
    int2 ee = edges[k + 4], ef = edges[k + 5], eg = edges[k + 6], eh = edges[k + 7];
    float x0 = e1[((size_t)ea.x << 6) + lane];
    float x1 = e1[((size_t)eb.x << 6) + lane];
    float x2 = e1[((size_t)ec.x << 6) + lane];
    float x3 = e1[((size_t)ed.x << 6) + lane];
    float x4 = e1[((size_t)ee.x << 6) + lane];
    float x5 = e1[((size_t)ef.x << 6) + lane];
    float x6 = e1[((size_t)eg.x << 6) + lane];
    float x7 = e1[((size_t)eh.x << 6) + lane];
    acc += __int_as_float(ea.y) * x0;
    acc += __int_as_float(eb.y) * x1;
    acc += __int_as_float(ec.y) * x2;
    acc += __int_as_float(ed.y) * x3;
    acc += __int_as_float(ee.y) * x4;
    acc += __int_as_float(ef.y) * x5;
    acc += __int_as_float(eg.y) * x6;
    acc += __int_as_float(eh.y) * x7;
  }
  for (; k < end; ++k) {
    int2 e = edges[k];
    acc += __int_as_float(e.y) * e1[((size_t)e.x << 6) + lane];
  }
  size_t o = ((size_t)wave << 6) + lane;
  float v0 = e0[o];
  float v1 = e1[o];
  e2[o] = acc;
  summed[o] = v0 + v1 + acc;
  e0out[o] = v0;
}

// ---------------- fallback: atomic path ----------------

__global__ void spmm_atomic_k(const int* __restrict__ row, const int* __restrict__ col,
                              const float* __restrict__ val, const float* __restrict__ x,
                              float* __restrict__ y, int nnz) {
  int wave = (blockIdx.x * blockDim.x + threadIdx.x) >> 6;
  int lane = threadIdx.x & 63;
  if (wave >= nnz) return;
  int r = row[wave]; int c = col[wave]; float v = val[wave];
  atomicAdd(&y[(size_t)r * DHID + lane], v * x[(size_t)c * DHID + lane]);
}

__global__ void sum_k(const float4* __restrict__ e0, const float4* __restrict__ e1,
                      const float4* __restrict__ e2, float4* __restrict__ summed,
                      float4* __restrict__ e0out, int n4) {
  int i = blockIdx.x * blockDim.x + threadIdx.x;
  if (i < n4) {
    float4 a = e0[i], b = e1[i], c = e2[i];
    float4 s;
    s.x = a.x + b.x + c.x;
    s.y = a.y + b.y + c.y;
    s.z = a.z + b.z + c.z;
    s.w = a.w + b.w + c.w;
    summed[i] = s;
    e0out[i] = a;
  }
}

extern "C" void kernel_launch(void* const* d_in, const int* in_sizes, int n_in,
                              void* d_out, int out_size, void* d_ws, size_t ws_size,
                              hipStream_t stream) {
  const int*   row = (const int*)d_in[0];
  const int*   col = (const int*)d_in[1];
  const float* val = (const float*)d_in[2];
  const float* emb = (const float*)d_in[3];
  int nnz = in_sizes[0];
  int n   = in_sizes[3] / DHID;
  size_t ND = (size_t)n * DHID;

  float* out    = (float*)d_out;
  float* summed = out;
  float* e0o    = out + ND;
  float* e1     = out + 2 * ND;
  float* e2     = out + 3 * ND;

  int B  = (n + RPB - 1) / RPB;     // buckets of 64 rows
  int chunk = (nnz + G_BLOCKS - 1) / G_BLOCKS;

  // carve workspace
  size_t o0 = 0;
  size_t histGB_off   = o0; o0 += align256((size_t)BMAX * G_BLOCKS * 4);
  size_t offGB_off    = o0; o0 += align256((size_t)BMAX * G_BLOCKS * 4);
  size_t btot_off     = o0; o0 += align256((size_t)BMAX * 4);
  size_t base_off     = o0; o0 += align256((size_t)(BMAX + 1) * 4);
  size_t rowstart_off = o0; o0 += align256((size_t)(n + 1) * 4);
  size_t stage_off    = o0; o0 += align256((size_t)nnz * 8);
  size_t edges_off    = o0; o0 += align256((size_t)nnz * 8);
  size_t need_sorted = o0;

  bool use_sorted = (ws_size >= need_sorted) && (B <= BMAX) && (n < (1 << 24));

  int rb = (int)((ND + 255) / 256);   // wave-per-row: n*64 threads
  int n4 = (int)(ND / 4);
  int sb = (n4 + 255) / 256;
  int wb = (int)(((size_t)nnz * 64 + 255) / 256);

  if (use_sorted) {
    uint8_t* w = (uint8_t*)d_ws;
    int*  histGB   = (int*)(w + histGB_off);
    int*  offGB    = (int*)(w + offGB_off);
    int*  btot     = (int*)(w + btot_off);
    int*  base     = (int*)(w + base_off);
    int*  rowstart = (int*)(w + rowstart_off);
    int2* stage    = (int2*)(w + stage_off);
    int2* edges    = (int2*)(w + edges_off);

    // phase A: partition into 64-row buckets, zero global atomics
    a1_hist_k<<<G_BLOCKS, 256, 0, stream>>>(row, histGB, nnz, B, chunk);
    scan_gb_k<<<B, 256, 0, stream>>>(histGB, offGB, btot, B);
    scan_b_k<<<1, 256, 0, stream>>>(btot, base, B);
    a2_scatter_k<<<G_BLOCKS, 256, 0, stream>>>(row, col, val, base, offGB, stage,
                                               nnz, B, chunk);
    // phase B: single fused within-bucket row grouping
    bgroup_k<<<B, 256, 0, stream>>>(base, stage, edges, rowstart, n, nnz);

    // SpMM x2 (layer 2 fuses the e0+e1+e2 epilogue)
    spmm_k<<<rb, 256, 0, stream>>>(rowstart, edges, emb, e1, n);
    spmm_fused_k<<<rb, 256, 0, stream>>>(rowstart, edges, emb, e1, e2, summed, e0o, n);
  } else {
    zero_f32<<<(int)((ND + 255) / 256), 256, 0, stream>>>(e1, ND);
    spmm_atomic_k<<<wb, 256, 0, stream>>>(row, col, val, emb, e1, nnz);
    zero_f32<<<(int)((ND + 255) / 256), 256, 0, stream>>>(e2, ND);
    spmm_atomic_k<<<wb, 256, 0, stream>>>(row, col, val, e1, e2, nnz);
    sum_k<<<sb, 256, 0, stream>>>((const float4*)emb, (const float4*)e1,
                                  (const float4*)e2, (float4*)summed,
                                  (float4*)e0o, n4);
  }
}

// Round 6
// 433.124 us; speedup vs baseline: 5.9864x; 1.1364x over previous
//
#include <hip/hip_runtime.h>
#include <stdint.h>

#define DHID 64       // hidden dim, fixed by problem
#define G_BLOCKS 1024 // blocks in phase-A partition kernels
#define BMAX 1024     // max buckets (bucket = 128 rows; n <= 131072)
#define RPB 128       // rows per bucket

static inline size_t align256(size_t x) { return (x + 255) & ~(size_t)255; }

// ---------------- generic helpers ----------------

__global__ void zero_f32(float* __restrict__ p, size_t n) {
  size_t i = (size_t)blockIdx.x * blockDim.x + threadIdx.x;
  if (i < n) p[i] = 0.f;
}

// ---------------- phase A: bucket partition (bucket = row >> 7) ----------------

// per-(block,bucket) histogram; LDS atomics only. 4x unrolled for MLP.
__global__ __launch_bounds__(256) void
a1_hist_k(const int* __restrict__ row, int* __restrict__ histGB,
          int nnz, int B, int chunk) {
  __shared__ int h[BMAX];
  for (int i = threadIdx.x; i < B; i += 256) h[i] = 0;
  __syncthreads();
  int g = blockIdx.x;
  int s = g * chunk, e = min(nnz, s + chunk);
  int j = s + threadIdx.x;
  for (; j + 768 < e; j += 1024) {
    int r0 = row[j], r1 = row[j + 256], r2 = row[j + 512], r3 = row[j + 768];
    atomicAdd(&h[r0 >> 7], 1);
    atomicAdd(&h[r1 >> 7], 1);
    atomicAdd(&h[r2 >> 7], 1);
    atomicAdd(&h[r3 >> 7], 1);
  }
  for (; j < e; j += 256)
    atomicAdd(&h[row[j] >> 7], 1);
  __syncthreads();
  for (int i = threadIdx.x; i < B; i += 256)
    histGB[i * G_BLOCKS + g] = h[i];
}

// exclusive scan across the 1024 blocks within each bucket; one block per bucket,
// 4 values per thread.
__global__ __launch_bounds__(256) void
scan_gb_k(const int* __restrict__ histGB, int* __restrict__ offGB,
          int* __restrict__ btot, int B) {
  __shared__ int wsum[4];
  int b = blockIdx.x, t = threadIdx.x, lane = t & 63, w = t >> 6;
  int v[4];
  int s4 = 0;
#pragma unroll
  for (int i = 0; i < 4; ++i) {
    v[i] = histGB[b * G_BLOCKS + t * 4 + i];
    s4 += v[i];
  }
  int incl = s4;
#pragma unroll
  for (int off = 1; off < 64; off <<= 1) {
    int u = __shfl_up(incl, off);
    if (lane >= off) incl += u;
  }
  if (lane == 63) wsum[w] = incl;
  __syncthreads();
  int run = incl - s4;
  for (int w2 = 0; w2 < w; ++w2) run += wsum[w2];
#pragma unroll
  for (int i = 0; i < 4; ++i) {
    offGB[b * G_BLOCKS + t * 4 + i] = run;
    run += v[i];
  }
  if (t == 0) btot[b] = wsum[0] + wsum[1] + wsum[2] + wsum[3];
}

// exclusive scan of bucket totals -> base[0..B], base[B] = nnz.
// one block, 256 threads, 8 elements/thread (covers B <= 2048).
__global__ void scan_b_k(const int* __restrict__ btot, int* __restrict__ base, int B) {
  __shared__ int wsum[4];
  int t = threadIdx.x, lane = t & 63, w = t >> 6;
  int v[8];
  int s = 0;
#pragma unroll
  for (int i = 0; i < 8; ++i) {
    int idx = t * 8 + i;
    v[i] = (idx < B) ? btot[idx] : 0;
    s += v[i];
  }
  int incl = s;
#pragma unroll
  for (int off = 1; off < 64; off <<= 1) {
    int u = __shfl_up(incl, off);
    if (lane >= off) incl += u;
  }
  if (lane == 63) wsum[w] = incl;
  __syncthreads();
  int run = incl - s;
  for (int w2 = 0; w2 < w; ++w2) run += wsum[w2];
#pragma unroll
  for (int i = 0; i < 8; ++i) {
    int idx = t * 8 + i;
    if (idx <= B) base[idx] = run;
    run += v[i];
  }
}

// scatter edges into bucket regions; each block writes only its private quota
// window per bucket (base[b] + offGB[b][g] ...), so lines merge in L2/L3.
// No global atomics. payload packs row-low-7 into bits 24..30 (col < 2^24).
// 4x unrolled for MLP (4 independent ds_add_rtn + store chains in flight).
__global__ __launch_bounds__(256) void
a2_scatter_k(const int* __restrict__ row, const int* __restrict__ col,
             const float* __restrict__ val, const int* __restrict__ base,
             const int* __restrict__ offGB, int2* __restrict__ stage,
             int nnz, int B, int chunk) {
  __shared__ int cur[BMAX];
  int g = blockIdx.x;
  for (int i = threadIdx.x; i < B; i += 256)
    cur[i] = base[i] + offGB[i * G_BLOCKS + g];
  __syncthreads();
  int s = g * chunk, e = min(nnz, s + chunk);
  int j = s + threadIdx.x;
  for (; j + 768 < e; j += 1024) {
    int r0 = row[j], r1 = row[j + 256], r2 = row[j + 512], r3 = row[j + 768];
    int c0 = col[j], c1 = col[j + 256], c2 = col[j + 512], c3 = col[j + 768];
    float v0 = val[j], v1 = val[j + 256], v2 = val[j + 512], v3 = val[j + 768];
    int p0 = atomicAdd(&cur[r0 >> 7], 1);
    int p1 = atomicAdd(&cur[r1 >> 7], 1);
    int p2 = atomicAdd(&cur[r2 >> 7], 1);
    int p3 = atomicAdd(&cur[r3 >> 7], 1);
    int2 q0; q0.x = ((r0 & 127) << 24) | c0; q0.y = __float_as_int(v0);
    int2 q1; q1.x = ((r1 & 127) << 24) | c1; q1.y = __float_as_int(v1);
    int2 q2; q2.x = ((r2 & 127) << 24) | c2; q2.y = __float_as_int(v2);
    int2 q3; q3.x = ((r3 & 127) << 24) | c3; q3.y = __float_as_int(v3);
    stage[p0] = q0;
    stage[p1] = q1;
    stage[p2] = q2;
    stage[p3] = q3;
  }
  for (; j < e; j += 256) {
    int r = row[j];
    int pos = atomicAdd(&cur[r >> 7], 1);
    int2 p;
    p.x = ((r & 127) << 24) | col[j];
    p.y = __float_as_int(val[j]);
    stage[pos] = p;
  }
}

// ---------------- phase B (fused): within-bucket row grouping, ONE kernel ----------------
// Per 128-row bucket: LDS histogram -> 2-wave scan -> emit rowstart -> re-read bucket
// (32KB, L2/L3-hot) -> scatter into private contiguous edges window.

__global__ __launch_bounds__(256) void
bgroup_k(const int* __restrict__ base, const int2* __restrict__ stage,
         int2* __restrict__ edges, int* __restrict__ rowstart, int n, int nnz) {
  __shared__ int h[RPB];
  __shared__ int cur[RPB];
  __shared__ int w0sum;
  int b = blockIdx.x, t = threadIdx.x;
  int lane = t & 63, w = t >> 6;
  if (t < RPB) h[t] = 0;
  __syncthreads();
  int s = base[b], e = base[b + 1];
  {
    int j = s + t;
    for (; j + 768 < e; j += 1024) {
      int a0 = ((unsigned)stage[j].x) >> 24;
      int a1 = ((unsigned)stage[j + 256].x) >> 24;
      int a2 = ((unsigned)stage[j + 512].x) >> 24;
      int a3 = ((unsigned)stage[j + 768].x) >> 24;
      atomicAdd(&h[a0], 1);
      atomicAdd(&h[a1], 1);
      atomicAdd(&h[a2], 1);
      atomicAdd(&h[a3], 1);
    }
    for (; j < e; j += 256)
      atomicAdd(&h[((unsigned)stage[j].x) >> 24], 1);
  }
  __syncthreads();
  int v = 0, incl = 0;
  if (t < RPB) {               // waves 0 and 1
    v = h[t];
    incl = v;
#pragma unroll
    for (int off = 1; off < 64; off <<= 1) {
      int u = __shfl_up(incl, off);
      if (lane >= off) incl += u;
    }
    if (t == 63) w0sum = incl;
  }
  __syncthreads();
  if (t < RPB) {
    int excl = incl - v + ((w == 1) ? w0sum : 0);
    cur[t] = s + excl;
    int r = (b << 7) + t;
    if (r < n) rowstart[r] = s + excl;
  }
  if (b == 0 && t == 0) rowstart[n] = nnz;
  __syncthreads();
  {
    int j = s + t;
    for (; j + 768 < e; j += 1024) {
      int2 p0 = stage[j], p1 = stage[j + 256], p2 = stage[j + 512], p3 = stage[j + 768];
      int q0 = atomicAdd(&cur[((unsigned)p0.x) >> 24], 1);
      int q1 = atomicAdd(&cur[((unsigned)p1.x) >> 24], 1);
      int q2 = atomicAdd(&cur[((unsigned)p2.x) >> 24], 1);
      int q3 = atomicAdd(&cur[((unsigned)p3.x) >> 24], 1);
      int2 o0; o0.x = p0.x & 0xFFFFFF; o0.y = p0.y;
      int2 o1; o1.x = p1.x & 0xFFFFFF; o1.y = p1.y;
      int2 o2; o2.x = p2.x & 0xFFFFFF; o2.y = p2.y;
      int2 o3; o3.x = p3.x & 0xFFFFFF; o3.y = p3.y;
      edges[q0] = o0;
      edges[q1] = o1;
      edges[q2] = o2;
      edges[q3] = o3;
    }
    for (; j < e; j += 256) {
      int2 p = stage[j];
      int pos = atomicAdd(&cur[((unsigned)p.x) >> 24], 1);
      int2 q;
      q.x = p.x & 0xFFFFFF;
      q.y = p.y;
      edges[pos] = q;
    }
  }
}

// ---------------- SpMM: one wave per row (round-0 proven shape, verbatim) ----------------

__global__ void spmm_k(const int* __restrict__ rowstart, const int2* __restrict__ edges,
                       const float* __restrict__ x, float* __restrict__ y, int n) {
  int wave = (blockIdx.x * blockDim.x + threadIdx.x) >> 6;
  int lane = threadIdx.x & 63;
  if (wave >= n) return;
  int start = __builtin_amdgcn_readfirstlane(rowstart[wave]);
  int end   = __builtin_amdgcn_readfirstlane(rowstart[wave + 1]);
  float acc = 0.f;
  int k = start;
  for (; k + 8 <= end; k += 8) {
    int2 e0 = edges[k + 0], e1 = edges[k + 1], e2 = edges[k + 2], e3 = edges[k + 3];
    int2 e4 = edges[k + 4], e5 = edges[k + 5], e6 = edges[k + 6], e7 = edges[k + 7];
    float x0 = x[((size_t)e0.x << 6) + lane];
    float x1 = x[((size_t)e1.x << 6) + lane];
    float x2 = x[((size_t)e2.x << 6) + lane];
    float x3 = x[((size_t)e3.x << 6) + lane];
    float x4 = x[((size_t)e4.x << 6) + lane];
    float x5 = x[((size_t)e5.x << 6) + lane];
    float x6 = x[((size_t)e6.x << 6) + lane];
    float x7 = x[((size_t)e7.x << 6) + lane];
    acc += __int_as_float(e0.y) * x0;
    acc += __int_as_float(e1.y) * x1;
    acc += __int_as_float(e2.y) * x2;
    acc += __int_as_float(e3.y) * x3;
    acc += __int_as_float(e4.y) * x4;
    acc += __int_as_float(e5.y) * x5;
    acc += __int_as_float(e6.y) * x6;
    acc += __int_as_float(e7.y) * x7;
  }
  for (; k < end; ++k) {
    int2 e = edges[k];
    acc += __int_as_float(e.y) * x[((size_t)e.x << 6) + lane];
  }
  y[((size_t)wave << 6) + lane] = acc;
}

__global__ void spmm_fused_k(const int* __restrict__ rowstart, const int2* __restrict__ edges,
                             const float* __restrict__ e0, const float* __restrict__ e1,
                             float* __restrict__ e2, float* __restrict__ summed,
                             float* __restrict__ e0out, int n) {
  int wave = (blockIdx.x * blockDim.x + threadIdx.x) >> 6;
  int lane = threadIdx.x & 63;
  if (wave >= n) return;
  int start = __builtin_amdgcn_readfirstlane(rowstart[wave]);
  int end   = __builtin_amdgcn_readfirstlane(rowstart[wave + 1]);
  float acc = 0.f;
  int k = start;
  for (; k + 8 <= end; k += 8) {
    int2 ea = edges[k + 0], eb = edges[k + 1], ec = edges[k + 2], ed = edges[k + 3];
    int2 ee = edges[k + 4], ef = edges[k + 5], eg = edges[k + 6], eh = edges[k + 7];
    float x0 = e1[((size_t)ea.x << 6) + lane];
    float x1 = e1[((size_t)eb.x << 6) + lane];
    float x2 = e1[((size_t)ec.x << 6) + lane];
    float x3 = e1[((size_t)ed.x << 6) + lane];
    float x4 = e1[((size_t)ee.x << 6) + lane];
    float x5 = e1[((size_t)ef.x << 6) + lane];
    float x6 = e1[((size_t)eg.x << 6) + lane];
    float x7 = e1[((size_t)eh.x << 6) + lane];
    acc += __int_as_float(ea.y) * x0;
    acc += __int_as_float(eb.y) * x1;
    acc += __int_as_float(ec.y) * x2;
    acc += __int_as_float(ed.y) * x3;
    acc += __int_as_float(ee.y) * x4;
    acc += __int_as_float(ef.y) * x5;
    acc += __int_as_float(eg.y) * x6;
    acc += __int_as_float(eh.y) * x7;
  }
  for (; k < end; ++k) {
    int2 e = edges[k];
    acc += __int_as_float(e.y) * e1[((size_t)e.x << 6) + lane];
  }
  size_t o = ((size_t)wave << 6) + lane;
  float v0 = e0[o];
  float v1 = e1[o];
  e2[o] = acc;
  summed[o] = v0 + v1 + acc;
  e0out[o] = v0;
}

// ---------------- fallback: atomic path ----------------

__global__ void spmm_atomic_k(const int* __restrict__ row, const int* __restrict__ col,
                              const float* __restrict__ val, const float* __restrict__ x,
                              float* __restrict__ y, int nnz) {
  int wave = (blockIdx.x * blockDim.x + threadIdx.x) >> 6;
  int lane = threadIdx.x & 63;
  if (wave >= nnz) return;
  int r = row[wave]; int c = col[wave]; float v = val[wave];
  atomicAdd(&y[(size_t)r * DHID + lane], v * x[(size_t)c * DHID + lane]);
}

__global__ void sum_k(const float4* __restrict__ e0, const float4* __restrict__ e1,
                      const float4* __restrict__ e2, float4* __restrict__ summed,
                      float4* __restrict__ e0out, int n4) {
  int i = blockIdx.x * blockDim.x + threadIdx.x;
  if (i < n4) {
    float4 a = e0[i], b = e1[i], c = e2[i];
    float4 s;
    s.x = a.x + b.x + c.x;
    s.y = a.y + b.y + c.y;
    s.z = a.z + b.z + c.z;
    s.w = a.w + b.w + c.w;
    summed[i] = s;
    e0out[i] = a;
  }
}

extern "C" void kernel_launch(void* const* d_in, const int* in_sizes, int n_in,
                              void* d_out, int out_size, void* d_ws, size_t ws_size,
                              hipStream_t stream) {
  const int*   row = (const int*)d_in[0];
  const int*   col = (const int*)d_in[1];
  const float* val = (const float*)d_in[2];
  const float* emb = (const float*)d_in[3];
  int nnz = in_sizes[0];
  int n   = in_sizes[3] / DHID;
  size_t ND = (size_t)n * DHID;

  float* out    = (float*)d_out;
  float* summed = out;
  float* e0o    = out + ND;
  float* e1     = out + 2 * ND;
  float* e2     = out + 3 * ND;

  int B  = (n + RPB - 1) / RPB;     // buckets of 128 rows
  int chunk = (nnz + G_BLOCKS - 1) / G_BLOCKS;

  // carve workspace (use runtime B, not BMAX, for the big tables)
  size_t o0 = 0;
  size_t histGB_off   = o0; o0 += align256((size_t)B * G_BLOCKS * 4);
  size_t offGB_off    = o0; o0 += align256((size_t)B * G_BLOCKS * 4);
  size_t btot_off     = o0; o0 += align256((size_t)B * 4);
  size_t base_off     = o0; o0 += align256((size_t)(B + 1) * 4);
  size_t rowstart_off = o0; o0 += align256((size_t)(n + 1) * 4);
  size_t stage_off    = o0; o0 += align256((size_t)nnz * 8);
  size_t edges_off    = o0; o0 += align256((size_t)nnz * 8);
  size_t need_sorted = o0;

  bool use_sorted = (ws_size >= need_sorted) && (B <= BMAX) && (n < (1 << 24));

  int rb = (int)((ND + 255) / 256);   // wave-per-row: n*64 threads
  int n4 = (int)(ND / 4);
  int sb = (n4 + 255) / 256;
  int wb = (int)(((size_t)nnz * 64 + 255) / 256);

  if (use_sorted) {
    uint8_t* w = (uint8_t*)d_ws;
    int*  histGB   = (int*)(w + histGB_off);
    int*  offGB    = (int*)(w + offGB_off);
    int*  btot     = (int*)(w + btot_off);
    int*  base     = (int*)(w + base_off);
    int*  rowstart = (int*)(w + rowstart_off);
    int2* stage    = (int2*)(w + stage_off);
    int2* edges    = (int2*)(w + edges_off);

    // phase A: partition into 128-row buckets, zero global atomics
    a1_hist_k<<<G_BLOCKS, 256, 0, stream>>>(row, histGB, nnz, B, chunk);
    scan_gb_k<<<B, 256, 0, stream>>>(histGB, offGB, btot, B);
    scan_b_k<<<1, 256, 0, stream>>>(btot, base, B);
    a2_scatter_k<<<G_BLOCKS, 256, 0, stream>>>(row, col, val, base, offGB, stage,
                                               nnz, B, chunk);
    // phase B: single fused within-bucket row grouping
    bgroup_k<<<B, 256, 0, stream>>>(base, stage, edges, rowstart, n, nnz);

    // SpMM x2 (layer 2 fuses the e0+e1+e2 epilogue)
    spmm_k<<<rb, 256, 0, stream>>>(rowstart, edges, emb, e1, n);
    spmm_fused_k<<<rb, 256, 0, stream>>>(rowstart, edges, emb, e1, e2, summed, e0o, n);
  } else {
    zero_f32<<<(int)((ND + 255) / 256), 256, 0, stream>>>(e1, ND);
    spmm_atomic_k<<<wb, 256, 0, stream>>>(row, col, val, emb, e1, nnz);
    zero_f32<<<(int)((ND + 255) / 256), 256, 0, stream>>>(e2, ND);
    spmm_atomic_k<<<wb, 256, 0, stream>>>(row, col, val, e1, e2, nnz);
    sum_k<<<sb, 256, 0, stream>>>((const float4*)emb, (const float4*)e1,
                                  (const float4*)e2, (float4*)summed,
                                  (float4*)e0o, n4);
  }
}

// Round 7
// 432.615 us; speedup vs baseline: 5.9935x; 1.0012x over previous
//
#include <hip/hip_runtime.h>
#include <stdint.h>

#define DHID 64       // hidden dim, fixed by problem
#define G_BLOCKS 1024 // blocks in phase-A partition kernels
#define BMAX 1024     // max buckets (bucket = 128 rows; n <= 131072)
#define RPB 128       // rows per bucket
#define CAP 4608      // LDS edge buffer per bucket (mean 4093 + ~8 sigma)

static inline size_t align256(size_t x) { return (x + 255) & ~(size_t)255; }

// ---------------- generic helpers ----------------

__global__ void zero_f32(float* __restrict__ p, size_t n) {
  size_t i = (size_t)blockIdx.x * blockDim.x + threadIdx.x;
  if (i < n) p[i] = 0.f;
}

// ---------------- phase A: bucket partition (bucket = row >> 7) ----------------
// (frozen from round 6 — verified)

__global__ __launch_bounds__(256) void
a1_hist_k(const int* __restrict__ row, int* __restrict__ histGB,
          int nnz, int B, int chunk) {
  __shared__ int h[BMAX];
  for (int i = threadIdx.x; i < B; i += 256) h[i] = 0;
  __syncthreads();
  int g = blockIdx.x;
  int s = g * chunk, e = min(nnz, s + chunk);
  int j = s + threadIdx.x;
  for (; j + 768 < e; j += 1024) {
    int r0 = row[j], r1 = row[j + 256], r2 = row[j + 512], r3 = row[j + 768];
    atomicAdd(&h[r0 >> 7], 1);
    atomicAdd(&h[r1 >> 7], 1);
    atomicAdd(&h[r2 >> 7], 1);
    atomicAdd(&h[r3 >> 7], 1);
  }
  for (; j < e; j += 256)
    atomicAdd(&h[row[j] >> 7], 1);
  __syncthreads();
  for (int i = threadIdx.x; i < B; i += 256)
    histGB[i * G_BLOCKS + g] = h[i];
}

__global__ __launch_bounds__(256) void
scan_gb_k(const int* __restrict__ histGB, int* __restrict__ offGB,
          int* __restrict__ btot, int B) {
  __shared__ int wsum[4];
  int b = blockIdx.x, t = threadIdx.x, lane = t & 63, w = t >> 6;
  int v[4];
  int s4 = 0;
#pragma unroll
  for (int i = 0; i < 4; ++i) {
    v[i] = histGB[b * G_BLOCKS + t * 4 + i];
    s4 += v[i];
  }
  int incl = s4;
#pragma unroll
  for (int off = 1; off < 64; off <<= 1) {
    int u = __shfl_up(incl, off);
    if (lane >= off) incl += u;
  }
  if (lane == 63) wsum[w] = incl;
  __syncthreads();
  int run = incl - s4;
  for (int w2 = 0; w2 < w; ++w2) run += wsum[w2];
#pragma unroll
  for (int i = 0; i < 4; ++i) {
    offGB[b * G_BLOCKS + t * 4 + i] = run;
    run += v[i];
  }
  if (t == 0) btot[b] = wsum[0] + wsum[1] + wsum[2] + wsum[3];
}

__global__ void scan_b_k(const int* __restrict__ btot, int* __restrict__ base, int B) {
  __shared__ int wsum[4];
  int t = threadIdx.x, lane = t & 63, w = t >> 6;
  int v[8];
  int s = 0;
#pragma unroll
  for (int i = 0; i < 8; ++i) {
    int idx = t * 8 + i;
    v[i] = (idx < B) ? btot[idx] : 0;
    s += v[i];
  }
  int incl = s;
#pragma unroll
  for (int off = 1; off < 64; off <<= 1) {
    int u = __shfl_up(incl, off);
    if (lane >= off) incl += u;
  }
  if (lane == 63) wsum[w] = incl;
  __syncthreads();
  int run = incl - s;
  for (int w2 = 0; w2 < w; ++w2) run += wsum[w2];
#pragma unroll
  for (int i = 0; i < 8; ++i) {
    int idx = t * 8 + i;
    if (idx <= B) base[idx] = run;
    run += v[i];
  }
}

__global__ __launch_bounds__(256) void
a2_scatter_k(const int* __restrict__ row, const int* __restrict__ col,
             const float* __restrict__ val, const int* __restrict__ base,
             const int* __restrict__ offGB, int2* __restrict__ stage,
             int nnz, int B, int chunk) {
  __shared__ int cur[BMAX];
  int g = blockIdx.x;
  for (int i = threadIdx.x; i < B; i += 256)
    cur[i] = base[i] + offGB[i * G_BLOCKS + g];
  __syncthreads();
  int s = g * chunk, e = min(nnz, s + chunk);
  int j = s + threadIdx.x;
  for (; j + 768 < e; j += 1024) {
    int r0 = row[j], r1 = row[j + 256], r2 = row[j + 512], r3 = row[j + 768];
    int c0 = col[j], c1 = col[j + 256], c2 = col[j + 512], c3 = col[j + 768];
    float v0 = val[j], v1 = val[j + 256], v2 = val[j + 512], v3 = val[j + 768];
    int p0 = atomicAdd(&cur[r0 >> 7], 1);
    int p1 = atomicAdd(&cur[r1 >> 7], 1);
    int p2 = atomicAdd(&cur[r2 >> 7], 1);
    int p3 = atomicAdd(&cur[r3 >> 7], 1);
    int2 q0; q0.x = ((r0 & 127) << 24) | c0; q0.y = __float_as_int(v0);
    int2 q1; q1.x = ((r1 & 127) << 24) | c1; q1.y = __float_as_int(v1);
    int2 q2; q2.x = ((r2 & 127) << 24) | c2; q2.y = __float_as_int(v2);
    int2 q3; q3.x = ((r3 & 127) << 24) | c3; q3.y = __float_as_int(v3);
    stage[p0] = q0;
    stage[p1] = q1;
    stage[p2] = q2;
    stage[p3] = q3;
  }
  for (; j < e; j += 256) {
    int r = row[j];
    int pos = atomicAdd(&cur[r >> 7], 1);
    int2 p;
    p.x = ((r & 127) << 24) | col[j];
    p.y = __float_as_int(val[j]);
    stage[pos] = p;
  }
}

// ---------------- SpMM with in-LDS bucket CSR build ----------------
// One block per 128-row bucket, 512 threads (8 waves x 16 rows).
// Build: read bucket's staged edges (L2/L3-hot) -> LDS hist -> scan -> LDS sorted
// edge list. Gather: round-0 proven shape; edge descriptors via uniform ds_read
// broadcast, accumulation in REGISTERS (no LDS atomics in the hot loop).

__global__ __launch_bounds__(512) void
spmm_csr_k(const int* __restrict__ base, const int2* __restrict__ stage,
           const float* __restrict__ x, float* __restrict__ y, int n) {
  __shared__ int2 ebuf[CAP];
  __shared__ int h[RPB], rowoff[RPB], cur[RPB];
  __shared__ int w0sum;
  int b = blockIdx.x, t = threadIdx.x;
  int lane = t & 63, w = t >> 6;
  if (t < RPB) h[t] = 0;
  __syncthreads();
  int s = __builtin_amdgcn_readfirstlane(base[b]);
  int e = __builtin_amdgcn_readfirstlane(base[b + 1]);
  int cnt = e - s;
  if (cnt <= CAP) {
    for (int j = s + t; j < e; j += 512)
      atomicAdd(&h[((unsigned)stage[j].x) >> 24], 1);
    __syncthreads();
    int v = 0, part = 0;
    if (t < RPB) {
      v = h[t];
      int incl = v;
#pragma unroll
      for (int off = 1; off < 64; off <<= 1) {
        int u = __shfl_up(incl, off);
        if (lane >= off) incl += u;
      }
      if (t == 63) w0sum = incl;
      part = incl - v;
    }
    __syncthreads();
    if (t < RPB) {
      int excl = part + ((t >= 64) ? w0sum : 0);
      rowoff[t] = excl;
      cur[t] = excl;
    }
    __syncthreads();
    for (int j = s + t; j < e; j += 512) {
      int2 p = stage[j];
      int r = ((unsigned)p.x) >> 24;
      int pos = atomicAdd(&cur[r], 1);
      int2 q; q.x = p.x & 0xFFFFFF; q.y = p.y;
      ebuf[pos] = q;
    }
    __syncthreads();
    // gather: wave w owns rows [w*16, w*16+16)
    for (int rr = w * 16; rr < w * 16 + 16; ++rr) {
      int R = (b << 7) + rr;
      if (R >= n) continue;
      int start = __builtin_amdgcn_readfirstlane(rowoff[rr]);
      int end   = __builtin_amdgcn_readfirstlane(cur[rr]);
      float acc = 0.f;
      int k = start;
      for (; k + 8 <= end; k += 8) {
        int2 e0 = ebuf[k + 0], e1 = ebuf[k + 1], e2 = ebuf[k + 2], e3 = ebuf[k + 3];
        int2 e4 = ebuf[k + 4], e5 = ebuf[k + 5], e6 = ebuf[k + 6], e7 = ebuf[k + 7];
        float x0 = x[((size_t)e0.x << 6) + lane];
        float x1 = x[((size_t)e1.x << 6) + lane];
        float x2 = x[((size_t)e2.x << 6) + lane];
        float x3 = x[((size_t)e3.x << 6) + lane];
        float x4 = x[((size_t)e4.x << 6) + lane];
        float x5 = x[((size_t)e5.x << 6) + lane];
        float x6 = x[((size_t)e6.x << 6) + lane];
        float x7 = x[((size_t)e7.x << 6) + lane];
        acc += __int_as_float(e0.y) * x0;
        acc += __int_as_float(e1.y) * x1;
        acc += __int_as_float(e2.y) * x2;
        acc += __int_as_float(e3.y) * x3;
        acc += __int_as_float(e4.y) * x4;
        acc += __int_as_float(e5.y) * x5;
        acc += __int_as_float(e6.y) * x6;
        acc += __int_as_float(e7.y) * x7;
      }
      for (; k < end; ++k) {
        int2 p = ebuf[k];
        acc += __int_as_float(p.y) * x[((size_t)p.x << 6) + lane];
      }
      y[((size_t)R << 6) + lane] = acc;
    }
  } else {
    // degenerate guard (cnt > CAP): never taken for this input; correct O(rows*cnt) scan
    for (int rr = w * 16; rr < w * 16 + 16; ++rr) {
      int R = (b << 7) + rr;
      if (R >= n) continue;
      float acc = 0.f;
      for (int j = s; j < e; ++j) {
        int2 p = stage[j];
        if ((int)(((unsigned)p.x) >> 24) == rr)
          acc += __int_as_float(p.y) * x[((size_t)(p.x & 0xFFFFFF) << 6) + lane];
      }
      y[((size_t)R << 6) + lane] = acc;
    }
  }
}

__global__ __launch_bounds__(512) void
spmm_csr_fused_k(const int* __restrict__ base, const int2* __restrict__ stage,
                 const float* __restrict__ e0g, const float* __restrict__ e1g,
                 float* __restrict__ e2g, float* __restrict__ summed,
                 float* __restrict__ e0out, int n) {
  __shared__ int2 ebuf[CAP];
  __shared__ int h[RPB], rowoff[RPB], cur[RPB];
  __shared__ int w0sum;
  int b = blockIdx.x, t = threadIdx.x;
  int lane = t & 63, w = t >> 6;
  if (t < RPB) h[t] = 0;
  __syncthreads();
  int s = __builtin_amdgcn_readfirstlane(base[b]);
  int e = __builtin_amdgcn_readfirstlane(base[b + 1]);
  int cnt = e - s;
  if (cnt <= CAP) {
    for (int j = s + t; j < e; j += 512)
      atomicAdd(&h[((unsigned)stage[j].x) >> 24], 1);
    __syncthreads();
    int v = 0, part = 0;
    if (t < RPB) {
      v = h[t];
      int incl = v;
#pragma unroll
      for (int off = 1; off < 64; off <<= 1) {
        int u = __shfl_up(incl, off);
        if (lane >= off) incl += u;
      }
      if (t == 63) w0sum = incl;
      part = incl - v;
    }
    __syncthreads();
    if (t < RPB) {
      int excl = part + ((t >= 64) ? w0sum : 0);
      rowoff[t] = excl;
      cur[t] = excl;
    }
    __syncthreads();
    for (int j = s + t; j < e; j += 512) {
      int2 p = stage[j];
      int r = ((unsigned)p.x) >> 24;
      int pos = atomicAdd(&cur[r], 1);
      int2 q; q.x = p.x & 0xFFFFFF; q.y = p.y;
      ebuf[pos] = q;
    }
    __syncthreads();
    for (int rr = w * 16; rr < w * 16 + 16; ++rr) {
      int R = (b << 7) + rr;
      if (R >= n) continue;
      int start = __builtin_amdgcn_readfirstlane(rowoff[rr]);
      int end   = __builtin_amdgcn_readfirstlane(cur[rr]);
      float acc = 0.f;
      int k = start;
      for (; k + 8 <= end; k += 8) {
        int2 ea = ebuf[k + 0], eb = ebuf[k + 1], ec = ebuf[k + 2], ed = ebuf[k + 3];
        int2 ee = ebuf[k + 4], ef = ebuf[k + 5], eg = ebuf[k + 6], eh = ebuf[k + 7];
        float x0 = e1g[((size_t)ea.x << 6) + lane];
        float x1 = e1g[((size_t)eb.x << 6) + lane];
        float x2 = e1g[((size_t)ec.x << 6) + lane];
        float x3 = e1g[((size_t)ed.x << 6) + lane];
        float x4 = e1g[((size_t)ee.x << 6) + lane];
        float x5 = e1g[((size_t)ef.x << 6) + lane];
        float x6 = e1g[((size_t)eg.x << 6) + lane];
        float x7 = e1g[((size_t)eh.x << 6) + lane];
        acc += __int_as_float(ea.y) * x0;
        acc += __int_as_float(eb.y) * x1;
        acc += __int_as_float(ec.y) * x2;
        acc += __int_as_float(ed.y) * x3;
        acc += __int_as_float(ee.y) * x4;
        acc += __int_as_float(ef.y) * x5;
        acc += __int_as_float(eg.y) * x6;
        acc += __int_as_float(eh.y) * x7;
      }
      for (; k < end; ++k) {
        int2 p = ebuf[k];
        acc += __int_as_float(p.y) * e1g[((size_t)p.x << 6) + lane];
      }
      size_t o = ((size_t)R << 6) + lane;
      float v0 = e0g[o];
      float v1 = e1g[o];
      e2g[o] = acc;
      summed[o] = v0 + v1 + acc;
      e0out[o] = v0;
    }
  } else {
    for (int rr = w * 16; rr < w * 16 + 16; ++rr) {
      int R = (b << 7) + rr;
      if (R >= n) continue;
      float acc = 0.f;
      for (int j = s; j < e; ++j) {
        int2 p = stage[j];
        if ((int)(((unsigned)p.x) >> 24) == rr)
          acc += __int_as_float(p.y) * e1g[((size_t)(p.x & 0xFFFFFF) << 6) + lane];
      }
      size_t o = ((size_t)R << 6) + lane;
      float v0 = e0g[o];
      float v1 = e1g[o];
      e2g[o] = acc;
      summed[o] = v0 + v1 + acc;
      e0out[o] = v0;
    }
  }
}

// ---------------- fallback: atomic path ----------------

__global__ void spmm_atomic_k(const int* __restrict__ row, const int* __restrict__ col,
                              const float* __restrict__ val, const float* __restrict__ x,
                              float* __restrict__ y, int nnz) {
  int wave = (blockIdx.x * blockDim.x + threadIdx.x) >> 6;
  int lane = threadIdx.x & 63;
  if (wave >= nnz) return;
  int r = row[wave]; int c = col[wave]; float v = val[wave];
  atomicAdd(&y[(size_t)r * DHID + lane], v * x[(size_t)c * DHID + lane]);
}

__global__ void sum_k(const float4* __restrict__ e0, const float4* __restrict__ e1,
                      const float4* __restrict__ e2, float4* __restrict__ summed,
                      float4* __restrict__ e0out, int n4) {
  int i = blockIdx.x * blockDim.x + threadIdx.x;
  if (i < n4) {
    float4 a = e0[i], b = e1[i], c = e2[i];
    float4 s;
    s.x = a.x + b.x + c.x;
    s.y = a.y + b.y + c.y;
    s.z = a.z + b.z + c.z;
    s.w = a.w + b.w + c.w;
    summed[i] = s;
    e0out[i] = a;
  }
}

extern "C" void kernel_launch(void* const* d_in, const int* in_sizes, int n_in,
                              void* d_out, int out_size, void* d_ws, size_t ws_size,
                              hipStream_t stream) {
  const int*   row = (const int*)d_in[0];
  const int*   col = (const int*)d_in[1];
  const float* val = (const float*)d_in[2];
  const float* emb = (const float*)d_in[3];
  int nnz = in_sizes[0];
  int n   = in_sizes[3] / DHID;
  size_t ND = (size_t)n * DHID;

  float* out    = (float*)d_out;
  float* summed = out;
  float* e0o    = out + ND;
  float* e1     = out + 2 * ND;
  float* e2     = out + 3 * ND;

  int B  = (n + RPB - 1) / RPB;     // buckets of 128 rows
  int chunk = (nnz + G_BLOCKS - 1) / G_BLOCKS;

  // carve workspace
  size_t o0 = 0;
  size_t histGB_off = o0; o0 += align256((size_t)B * G_BLOCKS * 4);
  size_t offGB_off  = o0; o0 += align256((size_t)B * G_BLOCKS * 4);
  size_t btot_off   = o0; o0 += align256((size_t)B * 4);
  size_t base_off   = o0; o0 += align256((size_t)(B + 1) * 4);
  size_t stage_off  = o0; o0 += align256((size_t)nnz * 8);
  size_t need_sorted = o0;

  bool use_sorted = (ws_size >= need_sorted) && (B <= BMAX) && (n < (1 << 24));

  int n4 = (int)(ND / 4);
  int sb = (n4 + 255) / 256;
  int wb = (int)(((size_t)nnz * 64 + 255) / 256);

  if (use_sorted) {
    uint8_t* w = (uint8_t*)d_ws;
    int*  histGB = (int*)(w + histGB_off);
    int*  offGB  = (int*)(w + offGB_off);
    int*  btot   = (int*)(w + btot_off);
    int*  base   = (int*)(w + base_off);
    int2* stage  = (int2*)(w + stage_off);

    // phase A: partition into 128-row buckets, zero global atomics
    a1_hist_k<<<G_BLOCKS, 256, 0, stream>>>(row, histGB, nnz, B, chunk);
    scan_gb_k<<<B, 256, 0, stream>>>(histGB, offGB, btot, B);
    scan_b_k<<<1, 256, 0, stream>>>(btot, base, B);
    a2_scatter_k<<<G_BLOCKS, 256, 0, stream>>>(row, col, val, base, offGB, stage,
                                               nnz, B, chunk);

    // SpMM x2 with in-LDS bucket CSR build (layer 2 fuses the epilogue)
    spmm_csr_k<<<B, 512, 0, stream>>>(base, stage, emb, e1, n);
    spmm_csr_fused_k<<<B, 512, 0, stream>>>(base, stage, emb, e1, e2, summed, e0o, n);
  } else {
    zero_f32<<<(int)((ND + 255) / 256), 256, 0, stream>>>(e1, ND);
    spmm_atomic_k<<<wb, 256, 0, stream>>>(row, col, val, emb, e1, nnz);
    zero_f32<<<(int)((ND + 255) / 256), 256, 0, stream>>>(e2, ND);
    spmm_atomic_k<<<wb, 256, 0, stream>>>(row, col, val, e1, e2, nnz);
    sum_k<<<sb, 256, 0, stream>>>((const float4*)emb, (const float4*)e1,
                                  (const float4*)e2, (float4*)summed,
                                  (float4*)e0o, n4);
  }
}